// Round 1
// baseline (2985.350 us; speedup 1.0000x reference)
//
#include <hip/hip_runtime.h>
#include <hip/hip_bf16.h>

#define NF 256
#define NH 128

// ---------------- degree / norm ----------------
__global__ void k_deg_init(float* deg, int N) {
  int i = blockIdx.x * blockDim.x + threadIdx.x;
  if (i < N) deg[i] = 1.0f;  // self-loop contribution
}

__global__ void k_deg_count(const int* __restrict__ dst, float* deg, int E) {
  int e = blockIdx.x * blockDim.x + threadIdx.x;
  if (e < E) atomicAdd(&deg[dst[e]], 1.0f);
}

__global__ void k_dinv(float* deg, int N) {
  int i = blockIdx.x * blockDim.x + threadIdx.x;
  if (i < N) deg[i] = rsqrtf(deg[i]);  // deg >= 1 always (self-loop)
}

// ---------------- GEMM1: h = x @ W1  (N x 256) @ (256 x 128) ----------------
// Block: 512 threads, tile 64 rows x 128 cols, per-thread 4x4, K staged in 64-chunks.
__global__ __launch_bounds__(512) void k_gemm1(
    const float* __restrict__ x, const float* __restrict__ W,
    float* __restrict__ h, int N) {
  __shared__ float Xl[64][64];   // 16 KB
  __shared__ float Wl[64][NH];   // 32 KB
  const int tid = threadIdx.x;
  const int row0 = blockIdx.x * 64;
  const int cg = tid & 31;   // cols cg*4 .. cg*4+3
  const int rg = tid >> 5;   // rows rg*4 .. rg*4+3
  float acc[4][4] = {};

  for (int kc = 0; kc < NF; kc += 64) {
    // stage X tile: 64 rows x 64 k
    {
      const int r  = tid >> 3;
      const int k4 = (tid & 7) << 2;
      const int grow = row0 + r;
      float4 a0 = make_float4(0.f, 0.f, 0.f, 0.f), a1 = a0;
      if (grow < N) {
        a0 = *reinterpret_cast<const float4*>(&x[(size_t)grow * NF + kc + k4]);
        a1 = *reinterpret_cast<const float4*>(&x[(size_t)grow * NF + kc + k4 + 32]);
      }
      *reinterpret_cast<float4*>(&Xl[r][k4])      = a0;
      *reinterpret_cast<float4*>(&Xl[r][k4 + 32]) = a1;
    }
    // stage W tile: 64 k x 128 cols
    {
      const int k  = tid >> 5;          // 0..15
      const int c4 = (tid & 31) << 2;   // 0..124
#pragma unroll
      for (int j = 0; j < 4; ++j) {
        *reinterpret_cast<float4*>(&Wl[k + j * 16][c4]) =
            *reinterpret_cast<const float4*>(&W[(size_t)(kc + k + j * 16) * NH + c4]);
      }
    }
    __syncthreads();

#pragma unroll 4
    for (int k = 0; k < 64; k += 4) {
      float xs[4][4], ws[4][4];
#pragma unroll
      for (int r = 0; r < 4; ++r) {
        float4 t = *reinterpret_cast<const float4*>(&Xl[rg * 4 + r][k]);
        xs[r][0] = t.x; xs[r][1] = t.y; xs[r][2] = t.z; xs[r][3] = t.w;
      }
#pragma unroll
      for (int kk = 0; kk < 4; ++kk) {
        float4 t = *reinterpret_cast<const float4*>(&Wl[k + kk][cg * 4]);
        ws[kk][0] = t.x; ws[kk][1] = t.y; ws[kk][2] = t.z; ws[kk][3] = t.w;
      }
#pragma unroll
      for (int kk = 0; kk < 4; ++kk)
#pragma unroll
        for (int r = 0; r < 4; ++r)
#pragma unroll
          for (int c = 0; c < 4; ++c)
            acc[r][c] = fmaf(xs[r][kk], ws[kk][c], acc[r][c]);
    }
    __syncthreads();
  }

#pragma unroll
  for (int r = 0; r < 4; ++r) {
    const int grow = row0 + rg * 4 + r;
    if (grow < N) {
      float4 o = make_float4(acc[r][0], acc[r][1], acc[r][2], acc[r][3]);
      *reinterpret_cast<float4*>(&h[(size_t)grow * NH + cg * 4]) = o;
    }
  }
}

// ---------------- agg init: agg = h * dinv^2 (self-loop term) ----------------
__global__ void k_agg_init(const float* __restrict__ h, const float* __restrict__ dinv,
                           float* __restrict__ agg, int N) {
  int t = blockIdx.x * blockDim.x + threadIdx.x;  // one float4 per thread
  int total = N * (NH / 4);
  if (t >= total) return;
  int i = t >> 5;  // 32 float4 per node
  float d = dinv[i];
  float dd = d * d;
  float4 v = reinterpret_cast<const float4*>(h)[t];
  float4 o = make_float4(v.x * dd, v.y * dd, v.z * dd, v.w * dd);
  reinterpret_cast<float4*>(agg)[t] = o;
}

// ---------------- scatter layer1: agg[dst] += norm * h[src] ----------------
__global__ void k_scatter1(const float* __restrict__ h, const int* __restrict__ ei,
                           const float* __restrict__ dinv, float* __restrict__ agg, int E) {
  int t = blockIdx.x * blockDim.x + threadIdx.x;
  int e = t >> 5;   // 32 threads / edge
  int j = t & 31;
  if (e >= E) return;
  int s = ei[e];
  int d = ei[E + e];
  float w = dinv[s] * dinv[d];
  float4 v = reinterpret_cast<const float4*>(h)[(size_t)s * 32 + j];
  float* a = &agg[(size_t)d * NH + j * 4];
  atomicAdd(a + 0, v.x * w);
  atomicAdd(a + 1, v.y * w);
  atomicAdd(a + 2, v.z * w);
  atomicAdd(a + 3, v.w * w);
}

// ---------------- Wc = W2 @ Wf ; Wc[128] = b2.Wf + bf ----------------
__global__ void k_wc(const float* __restrict__ W2, const float* __restrict__ Wf,
                     const float* __restrict__ b2, const float* __restrict__ bf,
                     float* __restrict__ Wc) {
  int i = threadIdx.x;  // 0..127
  float s = 0.f;
  for (int k = 0; k < NH; ++k) s += W2[i * NH + k] * Wf[k];
  Wc[i] = s;
  if (i == 0) {
    float c = 0.f;
    for (int k = 0; k < NH; ++k) c += b2[k] * Wf[k];
    Wc[NH] = c + bf[0];
  }
}

// ---------------- fused: z = relu(agg + b1) . Wc ; out init with self-loop ----------------
__global__ void k_z_out(const float* __restrict__ agg, const float* __restrict__ b1,
                        const float* __restrict__ Wc, const float* __restrict__ dinv,
                        float* __restrict__ z, float* __restrict__ out, int N) {
  int g = blockIdx.x * blockDim.x + threadIdx.x;
  int i = g >> 6;                    // one wave (64 lanes) per node
  int lane = threadIdx.x & 63;
  if (i >= N) return;
  const float* a = &agg[(size_t)i * NH];
  float v0 = fmaxf(a[lane] + b1[lane], 0.f);
  float v1 = fmaxf(a[lane + 64] + b1[lane + 64], 0.f);
  float s = v0 * Wc[lane] + v1 * Wc[lane + 64];
#pragma unroll
  for (int m = 32; m >= 1; m >>= 1) s += __shfl_xor(s, m, 64);
  if (lane == 0) {
    float d = dinv[i];
    z[i] = s;
    out[i] = s * d * d + Wc[NH];   // self-loop term + (b2.Wf + bf)
  }
}

// ---------------- scatter layer2 (scalar): out[dst] += norm * z[src] ----------------
__global__ void k_scatter2(const int* __restrict__ ei, const float* __restrict__ dinv,
                           const float* __restrict__ z, float* __restrict__ out, int E) {
  int e = blockIdx.x * blockDim.x + threadIdx.x;
  if (e >= E) return;
  int s = ei[e];
  int d = ei[E + e];
  atomicAdd(&out[d], dinv[s] * dinv[d] * z[s]);
}

extern "C" void kernel_launch(void* const* d_in, const int* in_sizes, int n_in,
                              void* d_out, int out_size, void* d_ws, size_t ws_size,
                              hipStream_t stream) {
  const float* x  = (const float*)d_in[0];
  const int*   ei = (const int*)d_in[1];
  const float* W1 = (const float*)d_in[2];
  const float* b1 = (const float*)d_in[3];
  const float* W2 = (const float*)d_in[4];
  const float* b2 = (const float*)d_in[5];
  const float* Wf = (const float*)d_in[6];
  const float* bf = (const float*)d_in[7];
  const int N = in_sizes[0] / NF;
  const int E = in_sizes[1] / 2;

  char* ws = (char*)d_ws;
  float* h    = (float*)(ws);
  float* agg  = (float*)(ws + (size_t)N * NH * 4);
  float* dinv = (float*)(ws + (size_t)N * NH * 8);
  float* z    = (float*)(ws + (size_t)N * NH * 8 + (size_t)N * 4);
  float* Wc   = (float*)(ws + (size_t)N * NH * 8 + (size_t)N * 8);
  float* out  = (float*)d_out;

  const int b = 256;
  k_deg_init <<<(N + b - 1) / b, b, 0, stream>>>(dinv, N);
  k_deg_count<<<(E + b - 1) / b, b, 0, stream>>>(ei + E, dinv, E);
  k_dinv     <<<(N + b - 1) / b, b, 0, stream>>>(dinv, N);
  k_gemm1    <<<(N + 63) / 64, 512, 0, stream>>>(x, W1, h, N);
  k_agg_init <<<((N * (NH / 4)) + b - 1) / b, b, 0, stream>>>(h, dinv, agg, N);
  k_scatter1 <<<(int)(((size_t)E * 32 + b - 1) / b), b, 0, stream>>>(h, ei, dinv, agg, E);
  k_wc       <<<1, 128, 0, stream>>>(W2, Wf, b2, bf, Wc);
  k_z_out    <<<(int)(((size_t)N * 64 + b - 1) / b), b, 0, stream>>>(agg, b1, Wc, dinv, z, out, N);
  k_scatter2 <<<(E + b - 1) / b, b, 0, stream>>>(ei, dinv, z, out, E);
}

// Round 2
// 460.245 us; speedup vs baseline: 6.4864x; 6.4864x over previous
//
#include <hip/hip_runtime.h>
#include <hip/hip_bf16.h>

#define NF 256
#define NH 128

// ---------------- zero deg + counter ----------------
__global__ void k_zero(int* deg, int* counter, int N) {
  int i = blockIdx.x * blockDim.x + threadIdx.x;
  if (i < N) deg[i] = 0;
  if (i == 0) *counter = 0;
}

// ---------------- degree count (int) ----------------
__global__ void k_deg_count(const int* __restrict__ dst, int* deg, int E) {
  int e = blockIdx.x * blockDim.x + threadIdx.x;
  if (e < E) atomicAdd(&deg[dst[e]], 1);
}

// ---------------- dinv = rsqrt(deg + 1) ----------------
__global__ void k_dinv(const int* __restrict__ deg, float* dinv, int N) {
  int i = blockIdx.x * blockDim.x + threadIdx.x;
  if (i < N) dinv[i] = rsqrtf((float)deg[i] + 1.0f);
}

// ---------------- bucket allocator: rowptr/cursor via wave-prefix + 1 atomic/wave ----------------
__global__ void k_alloc(const int* __restrict__ deg, int* rowptr, int* cursor,
                        int* counter, int N) {
  int i = blockIdx.x * blockDim.x + threadIdx.x;
  int lane = threadIdx.x & 63;
  int d = (i < N) ? deg[i] : 0;
  int pre = d;
#pragma unroll
  for (int m = 1; m < 64; m <<= 1) {
    int t = __shfl_up(pre, m, 64);
    if (lane >= m) pre += t;
  }
  int excl = pre - d;
  int base = 0;
  if (lane == 63) base = atomicAdd(counter, pre);  // pre == wave total at lane 63
  base = __shfl(base, 63, 64);
  if (i < N) {
    rowptr[i] = base + excl;
    cursor[i] = base + excl;
  }
}

// ---------------- fill CSR: (src, w) pairs bucketed by dst ----------------
__global__ void k_fill(const int* __restrict__ ei, const float* __restrict__ dinv,
                       int* cursor, int2* __restrict__ csr, int E) {
  int e = blockIdx.x * blockDim.x + threadIdx.x;
  if (e >= E) return;
  int s = ei[e];
  int d = ei[E + e];
  float w = dinv[s] * dinv[d];
  int p = atomicAdd(&cursor[d], 1);
  csr[p] = make_int2(s, __float_as_int(w));
}

// ---------------- GEMM1: h = x @ W1  (N x 256) @ (256 x 128) ----------------
__global__ __launch_bounds__(512) void k_gemm1(
    const float* __restrict__ x, const float* __restrict__ W,
    float* __restrict__ h, int N) {
  __shared__ float Xl[64][64];   // 16 KB
  __shared__ float Wl[64][NH];   // 32 KB
  const int tid = threadIdx.x;
  const int row0 = blockIdx.x * 64;
  const int cg = tid & 31;
  const int rg = tid >> 5;
  float acc[4][4] = {};

  for (int kc = 0; kc < NF; kc += 64) {
    {
      const int r  = tid >> 3;
      const int k4 = (tid & 7) << 2;
      const int grow = row0 + r;
      float4 a0 = make_float4(0.f, 0.f, 0.f, 0.f), a1 = a0;
      if (grow < N) {
        a0 = *reinterpret_cast<const float4*>(&x[(size_t)grow * NF + kc + k4]);
        a1 = *reinterpret_cast<const float4*>(&x[(size_t)grow * NF + kc + k4 + 32]);
      }
      *reinterpret_cast<float4*>(&Xl[r][k4])      = a0;
      *reinterpret_cast<float4*>(&Xl[r][k4 + 32]) = a1;
    }
    {
      const int k  = tid >> 5;
      const int c4 = (tid & 31) << 2;
#pragma unroll
      for (int j = 0; j < 4; ++j) {
        *reinterpret_cast<float4*>(&Wl[k + j * 16][c4]) =
            *reinterpret_cast<const float4*>(&W[(size_t)(kc + k + j * 16) * NH + c4]);
      }
    }
    __syncthreads();

#pragma unroll 4
    for (int k = 0; k < 64; k += 4) {
      float xs[4][4], ws[4][4];
#pragma unroll
      for (int r = 0; r < 4; ++r) {
        float4 t = *reinterpret_cast<const float4*>(&Xl[rg * 4 + r][k]);
        xs[r][0] = t.x; xs[r][1] = t.y; xs[r][2] = t.z; xs[r][3] = t.w;
      }
#pragma unroll
      for (int kk = 0; kk < 4; ++kk) {
        float4 t = *reinterpret_cast<const float4*>(&Wl[k + kk][cg * 4]);
        ws[kk][0] = t.x; ws[kk][1] = t.y; ws[kk][2] = t.z; ws[kk][3] = t.w;
      }
#pragma unroll
      for (int kk = 0; kk < 4; ++kk)
#pragma unroll
        for (int r = 0; r < 4; ++r)
#pragma unroll
          for (int c = 0; c < 4; ++c)
            acc[r][c] = fmaf(xs[r][kk], ws[kk][c], acc[r][c]);
    }
    __syncthreads();
  }

#pragma unroll
  for (int r = 0; r < 4; ++r) {
    const int grow = row0 + rg * 4 + r;
    if (grow < N) {
      float4 o = make_float4(acc[r][0], acc[r][1], acc[r][2], acc[r][3]);
      *reinterpret_cast<float4*>(&h[(size_t)grow * NH + cg * 4]) = o;
    }
  }
}

// ---------------- Wc = W2 @ Wf ; Wc[128] = b2.Wf + bf ----------------
__global__ void k_wc(const float* __restrict__ W2, const float* __restrict__ Wf,
                     const float* __restrict__ b2, const float* __restrict__ bf,
                     float* __restrict__ Wc) {
  int i = threadIdx.x;
  float s = 0.f;
  for (int k = 0; k < NH; ++k) s += W2[i * NH + k] * Wf[k];
  Wc[i] = s;
  if (i == 0) {
    float c = 0.f;
    for (int k = 0; k < NH; ++k) c += b2[k] * Wf[k];
    Wc[NH] = c + bf[0];
  }
}

// ---------------- fused layer1 gather + relu + dot(Wc): one wave per node ----------------
__global__ __launch_bounds__(256) void k_agg1_z(
    const float* __restrict__ h, const int* __restrict__ rowptr,
    const int* __restrict__ deg, const int2* __restrict__ csr,
    const float* __restrict__ dinv, const float* __restrict__ b1,
    const float* __restrict__ Wc, float* __restrict__ z,
    float* __restrict__ out, int N) {
  int g = blockIdx.x * blockDim.x + threadIdx.x;
  int i = g >> 6;           // wave per node
  int lane = threadIdx.x & 63;
  if (i >= N) return;
  const float2* h2 = reinterpret_cast<const float2*>(h);

  float d = dinv[i];
  float dd = d * d;
  // self-loop term
  float2 v = h2[(size_t)i * 64 + lane];
  float ax = dd * v.x, ay = dd * v.y;

  int beg = rowptr[i];
  int end = beg + deg[i];
  for (int k = beg; k < end; ++k) {
    int2 sw = csr[k];                       // wave-uniform address -> broadcast
    float w = __int_as_float(sw.y);
    float2 u = h2[(size_t)sw.x * 64 + lane];
    ax = fmaf(w, u.x, ax);
    ay = fmaf(w, u.y, ay);
  }

  const float2* b12 = reinterpret_cast<const float2*>(b1);
  const float2* wc2 = reinterpret_cast<const float2*>(Wc);
  float2 bb = b12[lane];
  float2 ww = wc2[lane];
  float r0 = fmaxf(ax + bb.x, 0.f);
  float r1 = fmaxf(ay + bb.y, 0.f);
  float s = r0 * ww.x + r1 * ww.y;
#pragma unroll
  for (int m = 32; m >= 1; m >>= 1) s += __shfl_xor(s, m, 64);
  if (lane == 0) {
    z[i] = s;
    out[i] = dd * s + Wc[NH];   // self-loop of layer2 + (b2.Wf + bf)
  }
}

// ---------------- layer2 gather (scalar): out[i] += sum w*z[src] ----------------
__global__ void k_out2(const int* __restrict__ rowptr, const int* __restrict__ deg,
                       const int2* __restrict__ csr, const float* __restrict__ z,
                       float* __restrict__ out, int N) {
  int i = blockIdx.x * blockDim.x + threadIdx.x;
  if (i >= N) return;
  int beg = rowptr[i];
  int end = beg + deg[i];
  float s = 0.f;
  for (int k = beg; k < end; ++k) {
    int2 sw = csr[k];
    s = fmaf(__int_as_float(sw.y), z[sw.x], s);
  }
  out[i] += s;   // out rewritten by k_agg1_z each call; only owner thread writes
}

extern "C" void kernel_launch(void* const* d_in, const int* in_sizes, int n_in,
                              void* d_out, int out_size, void* d_ws, size_t ws_size,
                              hipStream_t stream) {
  const float* x  = (const float*)d_in[0];
  const int*   ei = (const int*)d_in[1];
  const float* W1 = (const float*)d_in[2];
  const float* b1 = (const float*)d_in[3];
  const float* W2 = (const float*)d_in[4];
  const float* b2 = (const float*)d_in[5];
  const float* Wf = (const float*)d_in[6];
  const float* bf = (const float*)d_in[7];
  const int N = in_sizes[0] / NF;
  const int E = in_sizes[1] / 2;

  char* ws = (char*)d_ws;
  size_t off = 0;
  float* h      = (float*)(ws + off); off += (size_t)N * NH * 4;   // 51.2 MB
  int2*  csr    = (int2*)(ws + off);  off += (size_t)E * 8;        // 12.8 MB
  int*   deg    = (int*)(ws + off);   off += (size_t)N * 4;
  int*   rowptr = (int*)(ws + off);   off += (size_t)N * 4;
  int*   cursor = (int*)(ws + off);   off += (size_t)N * 4;
  float* dinv   = (float*)(ws + off); off += (size_t)N * 4;
  float* z      = (float*)(ws + off); off += (size_t)N * 4;
  float* Wc     = (float*)(ws + off); off += 132 * 4;
  int*   counter= (int*)(ws + off);   off += 16;
  float* out    = (float*)d_out;

  const int b = 256;
  k_zero     <<<(N + b - 1) / b, b, 0, stream>>>(deg, counter, N);
  k_deg_count<<<(E + b - 1) / b, b, 0, stream>>>(ei + E, deg, E);
  k_dinv     <<<(N + b - 1) / b, b, 0, stream>>>(deg, dinv, N);
  k_alloc    <<<(N + b - 1) / b, b, 0, stream>>>(deg, rowptr, cursor, counter, N);
  k_fill     <<<(E + b - 1) / b, b, 0, stream>>>(ei, dinv, cursor, csr, E);
  k_gemm1    <<<(N + 63) / 64, 512, 0, stream>>>(x, W1, h, N);
  k_wc       <<<1, 128, 0, stream>>>(W2, Wf, b2, bf, Wc);
  k_agg1_z   <<<(int)(((size_t)N * 64 + b - 1) / b), b, 0, stream>>>(
      h, rowptr, deg, csr, dinv, b1, Wc, z, out, N);
  k_out2     <<<(N + b - 1) / b, b, 0, stream>>>(rowptr, deg, csr, z, out, N);
}

// Round 3
// 387.510 us; speedup vs baseline: 7.7039x; 1.1877x over previous
//
#include <hip/hip_runtime.h>
#include <hip/hip_bf16.h>

#define NF 256
#define NH 128

typedef __attribute__((ext_vector_type(8))) short short8;
typedef __attribute__((ext_vector_type(4))) float float4v;

static __device__ __forceinline__ ushort f2bf(float f) {
  unsigned u = __float_as_uint(f);
  u = (u + 0x7fffu + ((u >> 16) & 1u)) >> 16;   // round-to-nearest-even
  return (ushort)u;
}
static __device__ __forceinline__ float bflo(unsigned u) { return __uint_as_float(u << 16); }
static __device__ __forceinline__ float bfhi(unsigned u) { return __uint_as_float(u & 0xffff0000u); }

// ---------------- zero deg + counter ----------------
__global__ void k_zero(int* deg, int* counter, int N) {
  int i = blockIdx.x * blockDim.x + threadIdx.x;
  if (i < N) deg[i] = 0;
  if (i == 0) *counter = 0;
}

// ---------------- degree count ----------------
__global__ void k_deg_count(const int* __restrict__ dst, int* deg, int E) {
  int e = blockIdx.x * blockDim.x + threadIdx.x;
  if (e < E) atomicAdd(&deg[dst[e]], 1);
}

// ---------------- dinv = rsqrt(deg + 1) ----------------
__global__ void k_dinv(const int* __restrict__ deg, float* dinv, int N) {
  int i = blockIdx.x * blockDim.x + threadIdx.x;
  if (i < N) dinv[i] = rsqrtf((float)deg[i] + 1.0f);
}

// ---------------- bucket allocator ----------------
__global__ void k_alloc(const int* __restrict__ deg, int* rowptr, int* cursor,
                        int* counter, int N) {
  int i = blockIdx.x * blockDim.x + threadIdx.x;
  int lane = threadIdx.x & 63;
  int d = (i < N) ? deg[i] : 0;
  int pre = d;
#pragma unroll
  for (int m = 1; m < 64; m <<= 1) {
    int t = __shfl_up(pre, m, 64);
    if (lane >= m) pre += t;
  }
  int excl = pre - d;
  int base = 0;
  if (lane == 63) base = atomicAdd(counter, pre);
  base = __shfl(base, 63, 64);
  if (i < N) {
    rowptr[i] = base + excl;
    cursor[i] = base + excl;
  }
}

// ---------------- fill CSR (src only) ----------------
__global__ void k_fill(const int* __restrict__ ei, int* cursor, int* __restrict__ csr, int E) {
  int e = blockIdx.x * blockDim.x + threadIdx.x;
  if (e >= E) return;
  int s = ei[e];
  int d = ei[E + e];
  int p = atomicAdd(&cursor[d], 1);
  csr[p] = s;
}

// ---------------- pack W1 into B-fragment layout (bf16) ----------------
// Wf[((KS*8 + t)*64 + lane)*8 + i] = bf16(W1[KS*32 + (lane>>4)*8 + i][t*16 + (lane&15)])
__global__ void k_wfrag(const float* __restrict__ W1, ushort* __restrict__ Wf) {
  int g = blockIdx.x * blockDim.x + threadIdx.x;
  if (g >= NF * NH) return;
  int i    = g & 7;
  int lane = (g >> 3) & 63;
  int t    = (g >> 9) & 7;
  int ks   = g >> 12;
  int k = ks * 32 + ((lane >> 4) << 3) + i;
  int c = t * 16 + (lane & 15);
  Wf[g] = f2bf(W1[(size_t)k * NH + c]);
}

// ---------------- GEMM1 (MFMA): hs = dinv * (x @ W1), bf16 output ----------------
__global__ __launch_bounds__(256) void k_gemm1(
    const float* __restrict__ x, const ushort* __restrict__ Wf,
    const float* __restrict__ dinv, ushort* __restrict__ hs, int N) {
  __shared__ ushort Xl[64][72];    // +8 pad: 2-way banks only
  __shared__ ushort Ol[64][136];
  const int tid = threadIdx.x;
  const int w = tid >> 6, l = tid & 63;
  const int row0 = blockIdx.x * 64;
  float4v acc[8];
#pragma unroll
  for (int t = 0; t < 8; ++t) acc[t] = (float4v){0.f, 0.f, 0.f, 0.f};

  const int arow = 16 * w + (l & 15);
  const int asub = (l >> 4) * 8;

  for (int kc = 0; kc < NF; kc += 64) {
    {  // stage X chunk 64 rows x 64 k, fp32 -> bf16
      const int r = tid >> 2, grow = row0 + r;
      const int c0 = (tid & 3) * 16;
#pragma unroll
      for (int q = 0; q < 4; ++q) {
        float4 v = make_float4(0.f, 0.f, 0.f, 0.f);
        if (grow < N)
          v = *reinterpret_cast<const float4*>(&x[(size_t)grow * NF + kc + c0 + q * 4]);
        ushort4 o = make_ushort4(f2bf(v.x), f2bf(v.y), f2bf(v.z), f2bf(v.w));
        *reinterpret_cast<ushort4*>(&Xl[r][c0 + q * 4]) = o;
      }
    }
    __syncthreads();
#pragma unroll
    for (int ks = 0; ks < 2; ++ks) {
      short8 a = *reinterpret_cast<const short8*>(&Xl[arow][ks * 32 + asub]);
      const int KS = (kc >> 5) + ks;
#pragma unroll
      for (int t = 0; t < 8; ++t) {
        short8 b = *reinterpret_cast<const short8*>(&Wf[(size_t)(((KS * 8 + t) * 64 + l)) * 8]);
        acc[t] = __builtin_amdgcn_mfma_f32_16x16x32_bf16(a, b, acc[t], 0, 0, 0);
      }
    }
    __syncthreads();
  }

  // epilogue: scale by dinv, bf16, transpose via LDS, coalesced store
  float dj[4];
#pragma unroll
  for (int j = 0; j < 4; ++j) {
    int grow = row0 + 16 * w + (l >> 4) * 4 + j;
    dj[j] = (grow < N) ? dinv[grow] : 0.f;
  }
#pragma unroll
  for (int t = 0; t < 8; ++t)
#pragma unroll
    for (int j = 0; j < 4; ++j)
      Ol[16 * w + (l >> 4) * 4 + j][16 * t + (l & 15)] = f2bf(acc[t][j] * dj[j]);
  __syncthreads();
  {
    const int r = tid >> 2, grow = row0 + r;
    if (grow < N) {
      uint* dsts = (uint*)hs;  // row = 64 uints
#pragma unroll
      for (int q = 0; q < 4; ++q) {
        uint4 v = *reinterpret_cast<const uint4*>(&Ol[r][(tid & 3) * 32 + q * 8]);
        *reinterpret_cast<uint4*>(&dsts[(size_t)grow * 64 + (tid & 3) * 16 + q * 4]) = v;
      }
    }
  }
}

// ---------------- Wc = W2 @ Wf ; Wc[128] = b2.Wf + bf ----------------
__global__ void k_wc(const float* __restrict__ W2, const float* __restrict__ Wf,
                     const float* __restrict__ b2, const float* __restrict__ bf,
                     float* __restrict__ Wc) {
  int i = threadIdx.x;
  float s = 0.f;
  for (int k = 0; k < NH; ++k) s += W2[i * NH + k] * Wf[k];
  Wc[i] = s;
  if (i == 0) {
    float c = 0.f;
    for (int k = 0; k < NH; ++k) c += b2[k] * Wf[k];
    Wc[NH] = c + bf[0];
  }
}

// ---------------- fused layer1 gather (weightless) + relu + dot(Wc) ----------------
__global__ __launch_bounds__(256) void k_agg1_z(
    const uint* __restrict__ hsu, const int* __restrict__ rowptr,
    const int* __restrict__ deg, const int* __restrict__ csr,
    const float* __restrict__ dinv, const float* __restrict__ b1,
    const float* __restrict__ Wc, float* __restrict__ zs,
    float* __restrict__ out, int N) {
  int g = blockIdx.x * blockDim.x + threadIdx.x;
  int i = g >> 6;             // wave per node
  int lane = threadIdx.x & 63;
  if (i >= N) return;

  unsigned u = hsu[(size_t)i * 64 + lane];   // self-loop term
  float ax = bflo(u), ay = bfhi(u);

  int k = rowptr[i], end = k + deg[i];
  for (; k + 1 < end; k += 2) {
    int s0 = csr[k], s1 = csr[k + 1];
    unsigned u0 = hsu[(size_t)s0 * 64 + lane];
    unsigned u1 = hsu[(size_t)s1 * 64 + lane];
    ax += bflo(u0); ay += bfhi(u0);
    ax += bflo(u1); ay += bfhi(u1);
  }
  if (k < end) {
    unsigned u0 = hsu[(size_t)csr[k] * 64 + lane];
    ax += bflo(u0); ay += bfhi(u0);
  }

  float d = dinv[i];
  float2 bb = reinterpret_cast<const float2*>(b1)[lane];
  float2 ww = reinterpret_cast<const float2*>(Wc)[lane];
  float r0 = fmaxf(fmaf(d, ax, bb.x), 0.f);
  float r1 = fmaxf(fmaf(d, ay, bb.y), 0.f);
  float s = r0 * ww.x + r1 * ww.y;
#pragma unroll
  for (int m = 32; m >= 1; m >>= 1) s += __shfl_xor(s, m, 64);
  if (lane == 0) {
    float zsv = d * s;                 // zs = dinv * z
    zs[i] = zsv;
    out[i] = d * zsv + Wc[NH];         // self-loop of layer2 + (b2.Wf + bf)
  }
}

// ---------------- layer2 gather: out[i] += dinv[i] * sum zs[src] ----------------
__global__ void k_out2(const int* __restrict__ rowptr, const int* __restrict__ deg,
                       const int* __restrict__ csr, const float* __restrict__ zs,
                       const float* __restrict__ dinv, float* __restrict__ out, int N) {
  int i = blockIdx.x * blockDim.x + threadIdx.x;
  if (i >= N) return;
  int k = rowptr[i], end = k + deg[i];
  float s = 0.f;
  for (; k < end; ++k) s += zs[csr[k]];
  out[i] += dinv[i] * s;
}

extern "C" void kernel_launch(void* const* d_in, const int* in_sizes, int n_in,
                              void* d_out, int out_size, void* d_ws, size_t ws_size,
                              hipStream_t stream) {
  const float* x  = (const float*)d_in[0];
  const int*   ei = (const int*)d_in[1];
  const float* W1 = (const float*)d_in[2];
  const float* b1 = (const float*)d_in[3];
  const float* W2 = (const float*)d_in[4];
  const float* b2 = (const float*)d_in[5];
  const float* Wf = (const float*)d_in[6];
  const float* bf = (const float*)d_in[7];
  const int N = in_sizes[0] / NF;
  const int E = in_sizes[1] / 2;

  char* ws = (char*)d_ws;
  size_t off = 0;
  auto alloc = [&](size_t bytes) {
    void* p = ws + off;
    off = (off + bytes + 255) & ~(size_t)255;
    return p;
  };
  ushort* hs     = (ushort*)alloc((size_t)N * NH * 2);   // 25.6 MB
  ushort* Wfrag  = (ushort*)alloc((size_t)NF * NH * 2);  // 64 KB
  int*    csr    = (int*)alloc((size_t)E * 4);           // 6.4 MB
  int*    deg    = (int*)alloc((size_t)N * 4);
  int*    rowptr = (int*)alloc((size_t)N * 4);
  int*    cursor = (int*)alloc((size_t)N * 4);
  float*  dinv   = (float*)alloc((size_t)N * 4);
  float*  zs     = (float*)alloc((size_t)N * 4);
  float*  Wc     = (float*)alloc(132 * 4);
  int*    counter= (int*)alloc(16);
  float*  out    = (float*)d_out;

  const int b = 256;
  k_zero     <<<(N + b - 1) / b, b, 0, stream>>>(deg, counter, N);
  k_deg_count<<<(E + b - 1) / b, b, 0, stream>>>(ei + E, deg, E);
  k_dinv     <<<(N + b - 1) / b, b, 0, stream>>>(deg, dinv, N);
  k_alloc    <<<(N + b - 1) / b, b, 0, stream>>>(deg, rowptr, cursor, counter, N);
  k_fill     <<<(E + b - 1) / b, b, 0, stream>>>(ei, cursor, csr, E);
  k_wfrag    <<<(NF * NH + b - 1) / b, b, 0, stream>>>(W1, Wfrag);
  k_gemm1    <<<(N + 63) / 64, 256, 0, stream>>>(x, Wfrag, dinv, hs, N);
  k_wc       <<<1, 128, 0, stream>>>(W2, Wf, b2, bf, Wc);
  k_agg1_z   <<<(int)(((size_t)N * 64 + b - 1) / b), b, 0, stream>>>(
      (const uint*)hs, rowptr, deg, csr, dinv, b1, Wc, zs, out, N);
  k_out2     <<<(N + b - 1) / b, b, 0, stream>>>(rowptr, deg, csr, zs, dinv, out, N);
}

// Round 4
// 302.498 us; speedup vs baseline: 9.8690x; 1.2810x over previous
//
#include <hip/hip_runtime.h>
#include <hip/hip_bf16.h>

#define NF 256
#define NH 128
#define NPART 8

typedef __attribute__((ext_vector_type(8))) short short8;
typedef __attribute__((ext_vector_type(4))) float float4v;

static __device__ __forceinline__ ushort f2bf(float f) {
  unsigned u = __float_as_uint(f);
  u = (u + 0x7fffu + ((u >> 16) & 1u)) >> 16;   // round-to-nearest-even
  return (ushort)u;
}
static __device__ __forceinline__ float bflo(unsigned u) { return __uint_as_float(u << 16); }
static __device__ __forceinline__ float bfhi(unsigned u) { return __uint_as_float(u & 0xffff0000u); }

// ---------------- zero deg ----------------
__global__ void k_zero(int* deg, int N) {
  int i = blockIdx.x * blockDim.x + threadIdx.x;
  if (i < N) deg[i] = 0;
}

// ---------------- degree count, XCD-partitioned by dst range ----------------
__global__ void k_deg_p(const int* __restrict__ dst, int* deg, int E, int psz) {
  int part = blockIdx.x & (NPART - 1);
  int t = (blockIdx.x >> 3) * blockDim.x + threadIdx.x;
  int stride = (gridDim.x >> 3) * blockDim.x;
  int lo = part * psz, hi = lo + psz;
  for (int e = t; e < E; e += stride) {
    int d = dst[e];
    if (d >= lo && d < hi) atomicAdd(&deg[d], 1);
  }
}

// ---------------- scan pass 1: per-block sums of deg (1024/block) ----------------
__global__ __launch_bounds__(1024) void k_scan1(const int* __restrict__ deg, int* bsum, int N) {
  __shared__ int ws[16];
  int tid = threadIdx.x;
  int i = blockIdx.x * 1024 + tid;
  int d = (i < N) ? deg[i] : 0;
#pragma unroll
  for (int m = 1; m < 64; m <<= 1) d += __shfl_xor(d, m, 64);
  if ((tid & 63) == 0) ws[tid >> 6] = d;
  __syncthreads();
  if (tid < 64) {
    int v = (tid < 16) ? ws[tid] : 0;
#pragma unroll
    for (int m = 1; m < 16; m <<= 1) v += __shfl_xor(v, m, 64);
    if (tid == 0) bsum[blockIdx.x] = v;
  }
}

// ---------------- scan pass 2: exclusive scan of block sums (serial, nb ~ 98) ----------------
__global__ void k_scan2(int* bsum, int nb) {
  if (threadIdx.x == 0) {
    int run = 0;
    for (int b = 0; b < nb; ++b) { int v = bsum[b]; bsum[b] = run; run += v; }
  }
}

// ---------------- scan pass 3: rowptr/cursor = exclusive scan; dinv fused ----------------
__global__ __launch_bounds__(1024) void k_scan3(const int* __restrict__ deg,
                                                const int* __restrict__ bsum,
                                                int* rowptr, int* cursor,
                                                float* dinv, int N) {
  __shared__ int ws[16];
  int tid = threadIdx.x;
  int i = blockIdx.x * 1024 + tid;
  int lane = tid & 63, wid = tid >> 6;
  int d = (i < N) ? deg[i] : 0;
  int pre = d;
#pragma unroll
  for (int m = 1; m < 64; m <<= 1) {
    int t = __shfl_up(pre, m, 64);
    if (lane >= m) pre += t;
  }
  if (lane == 63) ws[wid] = pre;
  __syncthreads();
  if (wid == 0) {
    int v = (lane < 16) ? ws[lane] : 0;
#pragma unroll
    for (int m = 1; m < 16; m <<= 1) {
      int t = __shfl_up(v, m, 64);
      if (lane >= m) v += t;
    }
    if (lane < 16) ws[lane] = v;   // inclusive wave sums
  }
  __syncthreads();
  int waveoff = (wid == 0) ? 0 : ws[wid - 1];
  if (i < N) {
    int excl = (pre - d) + waveoff + bsum[blockIdx.x];
    rowptr[i] = excl;
    cursor[i] = excl;
    dinv[i] = rsqrtf((float)d + 1.0f);
  }
}

// ---------------- fill CSR (src only), XCD-partitioned by dst range ----------------
__global__ void k_fill_p(const int* __restrict__ ei, int* cursor,
                         int* __restrict__ csr, int E, int psz) {
  int part = blockIdx.x & (NPART - 1);
  int t = (blockIdx.x >> 3) * blockDim.x + threadIdx.x;
  int stride = (gridDim.x >> 3) * blockDim.x;
  int lo = part * psz, hi = lo + psz;
  for (int e = t; e < E; e += stride) {
    int d = ei[E + e];
    if (d >= lo && d < hi) {
      int s = ei[e];
      int p = atomicAdd(&cursor[d], 1);
      csr[p] = s;
    }
  }
}

// ---------------- weights: W1 B-fragments (blocks 0..127) + Wc (block 128) ----------------
// Wf[((KS*8 + t)*64 + lane)*8 + i] = bf16(W1[KS*32 + (lane>>4)*8 + i][t*16 + (lane&15)])
__global__ void k_weights(const float* __restrict__ W1, ushort* __restrict__ Wfr,
                          const float* __restrict__ W2, const float* __restrict__ Wf,
                          const float* __restrict__ b2, const float* __restrict__ bf,
                          float* __restrict__ Wc) {
  if (blockIdx.x < 128) {
    int g = blockIdx.x * 256 + threadIdx.x;
    int i    = g & 7;
    int lane = (g >> 3) & 63;
    int t    = (g >> 9) & 7;
    int ks   = g >> 12;
    int k = ks * 32 + ((lane >> 4) << 3) + i;
    int c = t * 16 + (lane & 15);
    Wfr[g] = f2bf(W1[(size_t)k * NH + c]);
  } else if (threadIdx.x < 128) {
    int i = threadIdx.x;
    float s = 0.f;
    for (int k = 0; k < NH; ++k) s += W2[i * NH + k] * Wf[k];
    Wc[i] = s;
    if (i == 0) {
      float c = 0.f;
      for (int k = 0; k < NH; ++k) c += b2[k] * Wf[k];
      Wc[NH] = c + bf[0];
    }
  }
}

// ---------------- GEMM1 (MFMA): hs = dinv * (x @ W1), bf16 output ----------------
__global__ __launch_bounds__(256) void k_gemm1(
    const float* __restrict__ x, const ushort* __restrict__ Wf,
    const float* __restrict__ dinv, ushort* __restrict__ hs, int N) {
  __shared__ ushort Xl[64][72];
  __shared__ ushort Ol[64][136];
  const int tid = threadIdx.x;
  const int w = tid >> 6, l = tid & 63;
  const int row0 = blockIdx.x * 64;
  float4v acc[8];
#pragma unroll
  for (int t = 0; t < 8; ++t) acc[t] = (float4v){0.f, 0.f, 0.f, 0.f};

  const int arow = 16 * w + (l & 15);
  const int asub = (l >> 4) * 8;

  for (int kc = 0; kc < NF; kc += 64) {
    {
      const int r = tid >> 2, grow = row0 + r;
      const int c0 = (tid & 3) * 16;
#pragma unroll
      for (int q = 0; q < 4; ++q) {
        float4 v = make_float4(0.f, 0.f, 0.f, 0.f);
        if (grow < N)
          v = *reinterpret_cast<const float4*>(&x[(size_t)grow * NF + kc + c0 + q * 4]);
        ushort4 o = make_ushort4(f2bf(v.x), f2bf(v.y), f2bf(v.z), f2bf(v.w));
        *reinterpret_cast<ushort4*>(&Xl[r][c0 + q * 4]) = o;
      }
    }
    __syncthreads();
#pragma unroll
    for (int ks = 0; ks < 2; ++ks) {
      short8 a = *reinterpret_cast<const short8*>(&Xl[arow][ks * 32 + asub]);
      const int KS = (kc >> 5) + ks;
#pragma unroll
      for (int t = 0; t < 8; ++t) {
        short8 b = *reinterpret_cast<const short8*>(&Wf[(size_t)(((KS * 8 + t) * 64 + l)) * 8]);
        acc[t] = __builtin_amdgcn_mfma_f32_16x16x32_bf16(a, b, acc[t], 0, 0, 0);
      }
    }
    __syncthreads();
  }

  float dj[4];
#pragma unroll
  for (int j = 0; j < 4; ++j) {
    int grow = row0 + 16 * w + (l >> 4) * 4 + j;
    dj[j] = (grow < N) ? dinv[grow] : 0.f;
  }
#pragma unroll
  for (int t = 0; t < 8; ++t)
#pragma unroll
    for (int j = 0; j < 4; ++j)
      Ol[16 * w + (l >> 4) * 4 + j][16 * t + (l & 15)] = f2bf(acc[t][j] * dj[j]);
  __syncthreads();
  {
    const int r = tid >> 2, grow = row0 + r;
    if (grow < N) {
      uint* dsts = (uint*)hs;
#pragma unroll
      for (int q = 0; q < 4; ++q) {
        uint4 v = *reinterpret_cast<const uint4*>(&Ol[r][(tid & 3) * 32 + q * 8]);
        *reinterpret_cast<uint4*>(&dsts[(size_t)grow * 64 + (tid & 3) * 16 + q * 4]) = v;
      }
    }
  }
}

// ---------------- fused layer1 gather + relu + dot(Wc): wave per node ----------------
__global__ __launch_bounds__(256) void k_agg1_z(
    const uint* __restrict__ hsu, const int* __restrict__ rowptr,
    const int* __restrict__ deg, const int* __restrict__ csr,
    const float* __restrict__ dinv, const float* __restrict__ b1,
    const float* __restrict__ Wc, float* __restrict__ zs,
    float* __restrict__ out, int N) {
  int g = blockIdx.x * blockDim.x + threadIdx.x;
  int i = g >> 6;
  int lane = threadIdx.x & 63;
  if (i >= N) return;

  unsigned u = hsu[(size_t)i * 64 + lane];   // self-loop
  float ax = bflo(u), ay = bfhi(u);

  int k = rowptr[i], end = k + deg[i];
  for (; k + 3 < end; k += 4) {
    int s0 = csr[k], s1 = csr[k + 1], s2 = csr[k + 2], s3 = csr[k + 3];
    unsigned u0 = hsu[(size_t)s0 * 64 + lane];
    unsigned u1 = hsu[(size_t)s1 * 64 + lane];
    unsigned u2 = hsu[(size_t)s2 * 64 + lane];
    unsigned u3 = hsu[(size_t)s3 * 64 + lane];
    ax += bflo(u0); ay += bfhi(u0);
    ax += bflo(u1); ay += bfhi(u1);
    ax += bflo(u2); ay += bfhi(u2);
    ax += bflo(u3); ay += bfhi(u3);
  }
  for (; k < end; ++k) {
    unsigned u0 = hsu[(size_t)csr[k] * 64 + lane];
    ax += bflo(u0); ay += bfhi(u0);
  }

  float d = dinv[i];
  float2 bb = reinterpret_cast<const float2*>(b1)[lane];
  float2 ww = reinterpret_cast<const float2*>(Wc)[lane];
  float r0 = fmaxf(fmaf(d, ax, bb.x), 0.f);
  float r1 = fmaxf(fmaf(d, ay, bb.y), 0.f);
  float s = r0 * ww.x + r1 * ww.y;
#pragma unroll
  for (int m = 32; m >= 1; m >>= 1) s += __shfl_xor(s, m, 64);
  if (lane == 0) {
    float zsv = d * s;
    zs[i] = zsv;
    out[i] = d * zsv + Wc[NH];
  }
}

// ---------------- layer2 gather: out[i] += dinv[i] * sum zs[src] ----------------
__global__ void k_out2(const int* __restrict__ rowptr, const int* __restrict__ deg,
                       const int* __restrict__ csr, const float* __restrict__ zs,
                       const float* __restrict__ dinv, float* __restrict__ out, int N) {
  int i = blockIdx.x * blockDim.x + threadIdx.x;
  if (i >= N) return;
  int k = rowptr[i], end = k + deg[i];
  float s = 0.f;
  for (; k < end; ++k) s += zs[csr[k]];
  out[i] += dinv[i] * s;
}

extern "C" void kernel_launch(void* const* d_in, const int* in_sizes, int n_in,
                              void* d_out, int out_size, void* d_ws, size_t ws_size,
                              hipStream_t stream) {
  const float* x  = (const float*)d_in[0];
  const int*   ei = (const int*)d_in[1];
  const float* W1 = (const float*)d_in[2];
  const float* b1 = (const float*)d_in[3];
  const float* W2 = (const float*)d_in[4];
  const float* b2 = (const float*)d_in[5];
  const float* Wf = (const float*)d_in[6];
  const float* bf = (const float*)d_in[7];
  const int N = in_sizes[0] / NF;
  const int E = in_sizes[1] / 2;
  const int psz = (N + NPART - 1) / NPART;
  const int nb = (N + 1023) / 1024;

  char* ws = (char*)d_ws;
  size_t off = 0;
  auto alloc = [&](size_t bytes) {
    void* p = ws + off;
    off = (off + bytes + 255) & ~(size_t)255;
    return p;
  };
  ushort* hs     = (ushort*)alloc((size_t)N * NH * 2);   // 25.6 MB
  ushort* Wfrag  = (ushort*)alloc((size_t)NF * NH * 2);  // 64 KB
  int*    csr    = (int*)alloc((size_t)E * 4);           // 6.4 MB
  int*    deg    = (int*)alloc((size_t)N * 4);
  int*    rowptr = (int*)alloc((size_t)N * 4);
  int*    cursor = (int*)alloc((size_t)N * 4);
  float*  dinv   = (float*)alloc((size_t)N * 4);
  float*  zs     = (float*)alloc((size_t)N * 4);
  float*  Wc     = (float*)alloc(132 * 4);
  int*    bsum   = (int*)alloc((size_t)nb * 4 + 64);
  float*  out    = (float*)d_out;

  const int b = 256;
  const int pgrid = NPART * 128;   // 8 XCD partitions x 128 blocks
  k_zero   <<<(N + b - 1) / b, b, 0, stream>>>(deg, N);
  k_deg_p  <<<pgrid, b, 0, stream>>>(ei + E, deg, E, psz);
  k_scan1  <<<nb, 1024, 0, stream>>>(deg, bsum, N);
  k_scan2  <<<1, 64, 0, stream>>>(bsum, nb);
  k_scan3  <<<nb, 1024, 0, stream>>>(deg, bsum, rowptr, cursor, dinv, N);
  k_fill_p <<<pgrid, b, 0, stream>>>(ei, cursor, csr, E, psz);
  k_weights<<<129, b, 0, stream>>>(W1, Wfrag, W2, Wf, b2, bf, Wc);
  k_gemm1  <<<(N + 63) / 64, 256, 0, stream>>>(x, Wfrag, dinv, hs, N);
  k_agg1_z <<<(int)(((size_t)N * 64 + b - 1) / b), b, 0, stream>>>(
      (const uint*)hs, rowptr, deg, csr, dinv, b1, Wc, zs, out, N);
  k_out2   <<<(N + b - 1) / b, b, 0, stream>>>(rowptr, deg, csr, zs, dinv, out, N);
}

// Round 5
// 282.506 us; speedup vs baseline: 10.5674x; 1.0708x over previous
//
#include <hip/hip_runtime.h>
#include <hip/hip_bf16.h>

#define NF 256
#define NH 128
#define NPART 8

typedef __attribute__((ext_vector_type(8))) short short8;
typedef __attribute__((ext_vector_type(4))) float float4v;

static __device__ __forceinline__ ushort f2bf(float f) {
  unsigned u = __float_as_uint(f);
  u = (u + 0x7fffu + ((u >> 16) & 1u)) >> 16;   // round-to-nearest-even
  return (ushort)u;
}
static __device__ __forceinline__ float bflo(unsigned u) { return __uint_as_float(u << 16); }
static __device__ __forceinline__ float bfhi(unsigned u) { return __uint_as_float(u & 0xffff0000u); }

static __device__ __forceinline__ short8 pack_bf8(float4 v0, float4 v1) {
  short8 r;
  r[0] = (short)f2bf(v0.x); r[1] = (short)f2bf(v0.y);
  r[2] = (short)f2bf(v0.z); r[3] = (short)f2bf(v0.w);
  r[4] = (short)f2bf(v1.x); r[5] = (short)f2bf(v1.y);
  r[6] = (short)f2bf(v1.z); r[7] = (short)f2bf(v1.w);
  return r;
}

// ---------------- init: zero deg + W1 B-fragments + Wc ----------------
__global__ __launch_bounds__(256) void k_init(
    int* deg, int N, int nzb,
    const float* __restrict__ W1, ushort* __restrict__ Wfr,
    const float* __restrict__ W2, const float* __restrict__ Wfv,
    const float* __restrict__ b2, const float* __restrict__ bfv,
    float* __restrict__ Wc) {
  int b = blockIdx.x;
  if (b < nzb) {
    int i = b * 256 + threadIdx.x;
    if (i < N) deg[i] = 0;
  } else if (b < nzb + 128) {
    int g = (b - nzb) * 256 + threadIdx.x;
    int ii   = g & 7;
    int lane = (g >> 3) & 63;
    int t    = (g >> 9) & 7;
    int ks   = g >> 12;
    int k = ks * 32 + ((lane >> 4) << 3) + ii;
    int c = t * 16 + (lane & 15);
    Wfr[g] = f2bf(W1[(size_t)k * NH + c]);
  } else {
    __shared__ float wl[NH];
    if (threadIdx.x < NH) wl[threadIdx.x] = Wfv[threadIdx.x];
    __syncthreads();
    if (threadIdx.x < NH) {
      int i = threadIdx.x;
      const float4* w4 = reinterpret_cast<const float4*>(&W2[(size_t)i * NH]);
      float s = 0.f;
#pragma unroll 8
      for (int k = 0; k < NH / 4; ++k) {
        float4 v = w4[k];
        s += v.x * wl[4 * k] + v.y * wl[4 * k + 1] + v.z * wl[4 * k + 2] + v.w * wl[4 * k + 3];
      }
      Wc[i] = s;
      if (i == 0) {
        float c = 0.f;
        for (int k = 0; k < NH; ++k) c += b2[k] * wl[k];
        Wc[NH] = c + bfv[0];
      }
    }
  }
}

// ---------------- degree count, XCD-partitioned, int4 ----------------
__global__ void k_deg_p(const int* __restrict__ ei, int* deg, int E, int psz) {
  int part = blockIdx.x & (NPART - 1);
  int t = (blockIdx.x >> 3) * blockDim.x + threadIdx.x;
  int stride = (gridDim.x >> 3) * blockDim.x;
  int lo = part * psz, hi = lo + psz;
  int E4 = E >> 2;
  const int4* dst4 = reinterpret_cast<const int4*>(ei + E);
  for (int q = t; q < E4; q += stride) {
    int4 d = dst4[q];
    if (d.x >= lo && d.x < hi) atomicAdd(&deg[d.x], 1);
    if (d.y >= lo && d.y < hi) atomicAdd(&deg[d.y], 1);
    if (d.z >= lo && d.z < hi) atomicAdd(&deg[d.z], 1);
    if (d.w >= lo && d.w < hi) atomicAdd(&deg[d.w], 1);
  }
  for (int e = (E4 << 2) + t; e < E; e += stride) {
    int d = ei[E + e];
    if (d >= lo && d < hi) atomicAdd(&deg[d], 1);
  }
}

// ---------------- scan pass 1: per-block sums of deg (1024/block) ----------------
__global__ __launch_bounds__(1024) void k_scan1(const int* __restrict__ deg, int* bsum, int N) {
  __shared__ int ws[16];
  int tid = threadIdx.x;
  int i = blockIdx.x * 1024 + tid;
  int d = (i < N) ? deg[i] : 0;
#pragma unroll
  for (int m = 1; m < 64; m <<= 1) d += __shfl_xor(d, m, 64);
  if ((tid & 63) == 0) ws[tid >> 6] = d;
  __syncthreads();
  if (tid < 64) {
    int v = (tid < 16) ? ws[tid] : 0;
#pragma unroll
    for (int m = 1; m < 16; m <<= 1) v += __shfl_xor(v, m, 64);
    if (tid == 0) bsum[blockIdx.x] = v;
  }
}

// ---------------- scan pass 2: rowptr/cursor; inline bsum prefix; dinv fused ----------------
__global__ __launch_bounds__(1024) void k_scan3(const int* __restrict__ deg,
                                                const int* __restrict__ bsum,
                                                int* rowptr, int* cursor,
                                                float* dinv, int N) {
  __shared__ int ws[17];
  int tid = threadIdx.x;
  int i = blockIdx.x * 1024 + tid;
  int lane = tid & 63, wid = tid >> 6;
  int d = (i < N) ? deg[i] : 0;
  int pre = d;
#pragma unroll
  for (int m = 1; m < 64; m <<= 1) {
    int t = __shfl_up(pre, m, 64);
    if (lane >= m) pre += t;
  }
  if (lane == 63) ws[wid] = pre;
  __syncthreads();
  if (wid == 0) {
    int v = (lane < 16) ? ws[lane] : 0;
#pragma unroll
    for (int m = 1; m < 16; m <<= 1) {
      int t = __shfl_up(v, m, 64);
      if (lane >= m) v += t;
    }
    if (lane < 16) ws[lane] = v;          // inclusive wave sums
  } else if (wid == 1) {
    int v = 0;
    for (int j = lane; j < blockIdx.x; j += 64) v += bsum[j];
#pragma unroll
    for (int m = 1; m < 64; m <<= 1) v += __shfl_xor(v, m, 64);
    if (lane == 0) ws[16] = v;            // block prefix
  }
  __syncthreads();
  int waveoff = (wid == 0) ? 0 : ws[wid - 1];
  if (i < N) {
    int excl = (pre - d) + waveoff + ws[16];
    rowptr[i] = excl;
    cursor[i] = excl;
    dinv[i] = rsqrtf((float)d + 1.0f);
  }
}

// ---------------- fill CSR (src only), XCD-partitioned, int4 ----------------
__global__ void k_fill_p(const int* __restrict__ ei, int* cursor,
                         int* __restrict__ csr, int E, int psz) {
  int part = blockIdx.x & (NPART - 1);
  int t = (blockIdx.x >> 3) * blockDim.x + threadIdx.x;
  int stride = (gridDim.x >> 3) * blockDim.x;
  int lo = part * psz, hi = lo + psz;
  int E4 = E >> 2;
  const int4* dst4 = reinterpret_cast<const int4*>(ei + E);
  const int4* src4 = reinterpret_cast<const int4*>(ei);
  for (int q = t; q < E4; q += stride) {
    int4 d = dst4[q];
    int4 s = src4[q];
    if (d.x >= lo && d.x < hi) csr[atomicAdd(&cursor[d.x], 1)] = s.x;
    if (d.y >= lo && d.y < hi) csr[atomicAdd(&cursor[d.y], 1)] = s.y;
    if (d.z >= lo && d.z < hi) csr[atomicAdd(&cursor[d.z], 1)] = s.z;
    if (d.w >= lo && d.w < hi) csr[atomicAdd(&cursor[d.w], 1)] = s.w;
  }
  for (int e = (E4 << 2) + t; e < E; e += stride) {
    int d = ei[E + e];
    if (d >= lo && d < hi) csr[atomicAdd(&cursor[d], 1)] = ei[e];
  }
}

// ---------------- GEMM1 (MFMA, no LDS staging): hs = dinv * (x @ W1), bf16 ----------------
__global__ __launch_bounds__(256) void k_gemm1(
    const float* __restrict__ x, const ushort* __restrict__ Wf,
    const float* __restrict__ dinv, ushort* __restrict__ hs, int N) {
  __shared__ ushort Ol[64][136];
  const int tid = threadIdx.x;
  const int w = tid >> 6, l = tid & 63;
  const int row0 = blockIdx.x * 64;
  const int arow = row0 + 16 * w + (l & 15);
  const int kg = l >> 4;
  const bool rv = arow < N;
  const float* xr = &x[(size_t)(rv ? arow : 0) * NF + kg * 8];

  short8 afr[8];
#pragma unroll
  for (int ks = 0; ks < 8; ++ks) {
    float4 v0 = make_float4(0.f, 0.f, 0.f, 0.f), v1 = v0;
    if (rv) {
      v0 = *reinterpret_cast<const float4*>(&xr[ks * 32]);
      v1 = *reinterpret_cast<const float4*>(&xr[ks * 32 + 4]);
    }
    afr[ks] = pack_bf8(v0, v1);
  }

  float4v acc[8];
#pragma unroll
  for (int t = 0; t < 8; ++t) acc[t] = (float4v){0.f, 0.f, 0.f, 0.f};
#pragma unroll
  for (int t = 0; t < 8; ++t) {
#pragma unroll
    for (int ks = 0; ks < 8; ++ks) {
      short8 b = *reinterpret_cast<const short8*>(&Wf[(size_t)(((ks * 8 + t) * 64 + l)) * 8]);
      acc[t] = __builtin_amdgcn_mfma_f32_16x16x32_bf16(afr[ks], b, acc[t], 0, 0, 0);
    }
  }

  // epilogue: scale by dinv, bf16, transpose via LDS, coalesced store
  float dj[4];
#pragma unroll
  for (int j = 0; j < 4; ++j) {
    int grow = row0 + 16 * w + (l >> 4) * 4 + j;
    dj[j] = (grow < N) ? dinv[grow] : 0.f;
  }
#pragma unroll
  for (int t = 0; t < 8; ++t)
#pragma unroll
    for (int j = 0; j < 4; ++j)
      Ol[16 * w + (l >> 4) * 4 + j][16 * t + (l & 15)] = f2bf(acc[t][j] * dj[j]);
  __syncthreads();
  {
    const int r = tid >> 2, grow = row0 + r;
    if (grow < N) {
      uint* dsts = (uint*)hs;
#pragma unroll
      for (int q = 0; q < 4; ++q) {
        uint4 v = *reinterpret_cast<const uint4*>(&Ol[r][(tid & 3) * 32 + q * 8]);
        *reinterpret_cast<uint4*>(&dsts[(size_t)grow * 64 + (tid & 3) * 16 + q * 4]) = v;
      }
    }
  }
}

// ---------------- fused layer1 gather + relu + dot(Wc): wave/node, half-wave edges ----------------
__global__ __launch_bounds__(256) void k_agg1_z(
    const uint2* __restrict__ hs2, const int* __restrict__ rowptr,
    const int* __restrict__ deg, const int* __restrict__ csr,
    const float* __restrict__ dinv, const float* __restrict__ b1,
    const float* __restrict__ Wc, float* __restrict__ zs,
    float* __restrict__ out, int N) {
  int g = blockIdx.x * blockDim.x + threadIdx.x;
  int i = g >> 6;
  if (i >= N) return;
  int lane = threadIdx.x & 63;
  int half = lane >> 5;
  int sub = lane & 31;

  float a0, a1, a2, a3;
  {  // self-loop: half 0 only
    uint2 u = hs2[(size_t)i * 32 + sub];
    if (half) { u.x = 0u; u.y = 0u; }
    a0 = bflo(u.x); a1 = bfhi(u.x); a2 = bflo(u.y); a3 = bfhi(u.y);
  }
  int kk = rowptr[i];
  const int end = kk + deg[i];

  for (; kk + 7 < end; kk += 8) {   // 8 edges/iter, 4 per half
    int c0 = csr[kk],     c1 = csr[kk + 1], c2 = csr[kk + 2], c3 = csr[kk + 3];
    int c4 = csr[kk + 4], c5 = csr[kk + 5], c6 = csr[kk + 6], c7 = csr[kk + 7];
    int sA = half ? c1 : c0;
    int sB = half ? c3 : c2;
    int sC = half ? c5 : c4;
    int sD = half ? c7 : c6;
    uint2 uA = hs2[(size_t)sA * 32 + sub];
    uint2 uB = hs2[(size_t)sB * 32 + sub];
    uint2 uC = hs2[(size_t)sC * 32 + sub];
    uint2 uD = hs2[(size_t)sD * 32 + sub];
    a0 += bflo(uA.x); a1 += bfhi(uA.x); a2 += bflo(uA.y); a3 += bfhi(uA.y);
    a0 += bflo(uB.x); a1 += bfhi(uB.x); a2 += bflo(uB.y); a3 += bfhi(uB.y);
    a0 += bflo(uC.x); a1 += bfhi(uC.x); a2 += bflo(uC.y); a3 += bfhi(uC.y);
    a0 += bflo(uD.x); a1 += bfhi(uD.x); a2 += bflo(uD.y); a3 += bfhi(uD.y);
  }
  for (; kk + 1 < end; kk += 2) {   // pairs
    int c0 = csr[kk], c1 = csr[kk + 1];
    int s = half ? c1 : c0;
    uint2 u = hs2[(size_t)s * 32 + sub];
    a0 += bflo(u.x); a1 += bfhi(u.x); a2 += bflo(u.y); a3 += bfhi(u.y);
  }
  if (kk < end) {                   // single leftover: half 0 only
    int c = csr[kk];
    uint2 u = hs2[(size_t)c * 32 + sub];
    if (half) { u.x = 0u; u.y = 0u; }
    a0 += bflo(u.x); a1 += bfhi(u.x); a2 += bflo(u.y); a3 += bfhi(u.y);
  }

  // combine halves
  a0 += __shfl_xor(a0, 32, 64);
  a1 += __shfl_xor(a1, 32, 64);
  a2 += __shfl_xor(a2, 32, 64);
  a3 += __shfl_xor(a3, 32, 64);

  float d = dinv[i];
  float4 bb = reinterpret_cast<const float4*>(b1)[sub];
  float4 ww = reinterpret_cast<const float4*>(Wc)[sub];
  float r0 = fmaxf(fmaf(d, a0, bb.x), 0.f);
  float r1 = fmaxf(fmaf(d, a1, bb.y), 0.f);
  float r2 = fmaxf(fmaf(d, a2, bb.z), 0.f);
  float r3 = fmaxf(fmaf(d, a3, bb.w), 0.f);
  float s = r0 * ww.x + r1 * ww.y + r2 * ww.z + r3 * ww.w;
#pragma unroll
  for (int m = 16; m >= 1; m >>= 1) s += __shfl_xor(s, m, 64);
  if (lane == 0) {
    float zsv = d * s;
    zs[i] = zsv;
    out[i] = d * zsv + Wc[NH];
  }
}

// ---------------- layer2 gather: out[i] += dinv[i] * sum zs[src] ----------------
__global__ void k_out2(const int* __restrict__ rowptr, const int* __restrict__ deg,
                       const int* __restrict__ csr, const float* __restrict__ zs,
                       const float* __restrict__ dinv, float* __restrict__ out, int N) {
  int i = blockIdx.x * blockDim.x + threadIdx.x;
  if (i >= N) return;
  int k = rowptr[i], end = k + deg[i];
  float s = 0.f;
  for (; k + 3 < end; k += 4) {
    float t0 = zs[csr[k]], t1 = zs[csr[k + 1]], t2 = zs[csr[k + 2]], t3 = zs[csr[k + 3]];
    s += (t0 + t1) + (t2 + t3);
  }
  for (; k < end; ++k) s += zs[csr[k]];
  out[i] += dinv[i] * s;
}

extern "C" void kernel_launch(void* const* d_in, const int* in_sizes, int n_in,
                              void* d_out, int out_size, void* d_ws, size_t ws_size,
                              hipStream_t stream) {
  const float* x  = (const float*)d_in[0];
  const int*   ei = (const int*)d_in[1];
  const float* W1 = (const float*)d_in[2];
  const float* b1 = (const float*)d_in[3];
  const float* W2 = (const float*)d_in[4];
  const float* b2 = (const float*)d_in[5];
  const float* Wf = (const float*)d_in[6];
  const float* bf = (const float*)d_in[7];
  const int N = in_sizes[0] / NF;
  const int E = in_sizes[1] / 2;
  const int psz = (N + NPART - 1) / NPART;
  const int nb = (N + 1023) / 1024;
  const int nzb = (N + 255) / 256;

  char* ws = (char*)d_ws;
  size_t off = 0;
  auto alloc = [&](size_t bytes) {
    void* p = ws + off;
    off = (off + bytes + 255) & ~(size_t)255;
    return p;
  };
  ushort* hs     = (ushort*)alloc((size_t)N * NH * 2);   // 25.6 MB
  ushort* Wfrag  = (ushort*)alloc((size_t)NF * NH * 2);  // 64 KB
  int*    csr    = (int*)alloc((size_t)E * 4);           // 6.4 MB
  int*    deg    = (int*)alloc((size_t)N * 4);
  int*    rowptr = (int*)alloc((size_t)N * 4);
  int*    cursor = (int*)alloc((size_t)N * 4);
  float*  dinv   = (float*)alloc((size_t)N * 4);
  float*  zs     = (float*)alloc((size_t)N * 4);
  float*  Wc     = (float*)alloc(132 * 4);
  int*    bsum   = (int*)alloc((size_t)nb * 4 + 64);
  float*  out    = (float*)d_out;

  const int b = 256;
  const int pgrid = NPART * 128;
  k_init   <<<nzb + 129, b, 0, stream>>>(deg, N, nzb, W1, Wfrag, W2, Wf, b2, bf, Wc);
  k_deg_p  <<<pgrid, b, 0, stream>>>(ei, deg, E, psz);
  k_scan1  <<<nb, 1024, 0, stream>>>(deg, bsum, N);
  k_scan3  <<<nb, 1024, 0, stream>>>(deg, bsum, rowptr, cursor, dinv, N);
  k_fill_p <<<pgrid, b, 0, stream>>>(ei, cursor, csr, E, psz);
  k_gemm1  <<<(N + 63) / 64, 256, 0, stream>>>(x, Wfrag, dinv, hs, N);
  k_agg1_z <<<(int)(((size_t)N * 64 + b - 1) / b), b, 0, stream>>>(
      (const uint2*)hs, rowptr, deg, csr, dinv, b1, Wc, zs, out, N);
  k_out2   <<<(N + b - 1) / b, b, 0, stream>>>(rowptr, deg, csr, zs, dinv, out, N);
}